// Round 1
// baseline (68.826 us; speedup 1.0000x reference)
//
#include <hip/hip_runtime.h>
#include <math.h>

// Problem constants (from reference)
#define MEMN 8
#define WDIM 41      // 1 + DEG*MEM = 1 + 5*8
#define BB   32
#define LL   4096
#define PADN 15      // 2*MEM - 1
#define TILE_T 8     // t-values per block
#define WIN 22       // TILE_T - 1 + 15  window length per b
#define STRIDE 23    // odd LDS stride (dwords) -> conflict-free over b

// out[b,t,:] = co[t] broadcast;  co[t] = sum_b sum_m xp[b,t+m] * acc_m
// where acc_m = W[m,0] + sum_mm ( W[m,1+5mm]*xp[b,t+m+mm]
//                + W[m,2+5mm] + W[m,3+5mm]*a + W[m,4+5mm]*a^2 + W[m,5+5mm]*a^3 )
// xp[b,j] = x[b, j-15] (zeros for j<15), a = |xp[b, t+m+mm]|.

__global__ __launch_bounds__(256)
void gmp_kernel(const float* __restrict__ x,   // (B, L, 2)
                const float* __restrict__ Wr,  // (MEM, WDIM)
                const float* __restrict__ Wi,  // (MEM, WDIM)
                float* __restrict__ out)       // (B, L, 2)
{
    __shared__ float s_re[BB * STRIDE];
    __shared__ float s_im[BB * STRIDE];
    __shared__ float s_am[BB * STRIDE];
    __shared__ float s_co[TILE_T][2];

    const int tid = threadIdx.x;
    const int t0  = blockIdx.x * TILE_T;

    // ---- stage x window into LDS: s_*[b*STRIDE + o] = xp[b, t0 + o], o in [0,WIN) ----
    {
        const int o  = tid & 31;   // 0..31 (only o < WIN active)
        const int b8 = tid >> 5;   // 0..7
        if (o < WIN) {
            const int g = t0 - PADN + o;   // global t-index into x
            #pragma unroll
            for (int it = 0; it < 4; ++it) {
                const int b = b8 + 8 * it;
                float re = 0.f, im = 0.f;
                if (g >= 0) {
                    const float2 v = *(const float2*)(x + ((size_t)b * LL + g) * 2);
                    re = v.x; im = v.y;
                }
                s_re[b * STRIDE + o] = re;
                s_im[b * STRIDE + o] = im;
                s_am[b * STRIDE + o] = sqrtf(re * re + im * im);
            }
        }
    }
    __syncthreads();

    // ---- compute: thread = (b, t-slot) ----
    const int b    = tid & 31;
    const int slot = tid >> 5;     // 0..7
    const int base = b * STRIDE + slot;

    float zr[15], zi[15], a1[15], a2[15], a3[15];
    #pragma unroll
    for (int k = 0; k < 15; ++k) {
        zr[k] = s_re[base + k];
        zi[k] = s_im[base + k];
        a1[k] = s_am[base + k];
        a2[k] = a1[k] * a1[k];
        a3[k] = a2[k] * a1[k];
    }

    float cr = 0.f, ci = 0.f;
    #pragma unroll
    for (int m = 0; m < MEMN; ++m) {
        float ar = Wr[m * WDIM];   // uniform -> s_load
        float ai = Wi[m * WDIM];
        #pragma unroll
        for (int mm = 0; mm < MEMN; ++mm) {
            const int k  = m + mm;
            const int wb = m * WDIM + 1 + 5 * mm;
            const float w0r = Wr[wb], w0i = Wi[wb];
            // c=0 channel: W * xp  (complex * complex)
            ar += w0r * zr[k] - w0i * zi[k];
            ai += w0r * zi[k] + w0i * zr[k];
            // c=1..4: cubic polynomial in amp (complex coeffs, real var)
            ar += Wr[wb + 1] + Wr[wb + 2] * a1[k] + Wr[wb + 3] * a2[k] + Wr[wb + 4] * a3[k];
            ai += Wi[wb + 1] + Wi[wb + 2] * a1[k] + Wi[wb + 3] * a2[k] + Wi[wb + 4] * a3[k];
        }
        // contrib += xp[b,t+m] * acc_m  (complex * complex)
        cr += zr[m] * ar - zi[m] * ai;
        ci += zr[m] * ai + zi[m] * ar;
    }

    // ---- butterfly reduce over b (lanes 0..31 within each 32-lane group) ----
    #pragma unroll
    for (int mask = 16; mask >= 1; mask >>= 1) {
        cr += __shfl_xor(cr, mask, 64);
        ci += __shfl_xor(ci, mask, 64);
    }
    if (b == 0) {
        s_co[slot][0] = cr;
        s_co[slot][1] = ci;
    }
    __syncthreads();

    // ---- broadcast write: out[b'][t0+j][:] for all 32 b' ----
    const int bw = tid >> 3;   // 0..31
    const int j  = tid & 7;    // 0..7
    float2 v;
    v.x = s_co[j][0];
    v.y = s_co[j][1];
    *(float2*)(out + ((size_t)bw * LL + t0 + j) * 2) = v;
}

extern "C" void kernel_launch(void* const* d_in, const int* in_sizes, int n_in,
                              void* d_out, int out_size, void* d_ws, size_t ws_size,
                              hipStream_t stream) {
    const float* x  = (const float*)d_in[0];
    // d_in[1] = h_0 : unused by the reference computation
    const float* Wr = (const float*)d_in[2];
    const float* Wi = (const float*)d_in[3];
    float* out = (float*)d_out;

    gmp_kernel<<<dim3(LL / TILE_T), dim3(256), 0, stream>>>(x, Wr, Wi, out);
}